// Round 9
// baseline (508.213 us; speedup 1.0000x reference)
//
#include <hip/hip_runtime.h>
#include <hip/hip_fp16.h>

// VQ codebook argmin: N=32768 queries x K=8192 codes x D=256 fp32.
// f16 hi/lo split (3 MFMA terms) => fp32-accurate dots on the matrix pipe;
// fused running argmin. Scaling (exact powers of 2, argmin-invariant):
// z*=2^4, e*=2^15; dist_scaled = 2^19*cb_sq - 2*acc.
//
// R9/R10: 4 WAVES/SIMD BY CONSTRUCTION. R8 tried 2x 64KB blocks/CU: the
// scheduler did NOT co-schedule them (Occupancy stayed 22% = 8 waves/CU)
// and halving the query tile doubled B cache traffic (FETCH 53->82MB).
// A workgroup's waves ARE guaranteed co-resident, so: ONE 1024-thread
// block per CU (16 waves = 4/SIMD), 128-query A panel (128KB LDS),
// grid 256. Per-wave code identical to R7 (63% MfmaUtil at 2/SIMD);
// wave (h,v,p) = row-half x col-half x ct-quarter. B traffic back to
// R7 level (h-twins share B via L2). launch_bounds(1024,4) caps VGPR
// at 128 (natural 96 -> no spill).
// (R9 bench was an infra failure - container acquisition; resubmitted.)

#define N_Q   32768
#define K_CB  8192
#define D_DIM 256

typedef _Float16 half8 __attribute__((ext_vector_type(8)));
typedef float    f32x4 __attribute__((ext_vector_type(4)));

__device__ __forceinline__ void gl_lds16(const _Float16* g, _Float16* l) {
  __builtin_amdgcn_global_load_lds(
      (const __attribute__((address_space(1))) unsigned int*)g,
      (__attribute__((address_space(3))) unsigned int*)l, 16, 0, 0);
}

// Frag-major layouts (half8 index):
//   zpk: ((qb*64 + q16*8 + kk)*2 + hl)*64 + l
//        = z[qb*128 + q16*16 + (l&15)][kk*32 + (l>>4)*8 + j]  (*2^4, hi/lo)
//   epk: ((c16*8  + kk)*2 + hl)*64 + l
//        = e[c16*16 + (l&15)][kk*32 + (l>>4)*8 + j]           (*2^15, hi/lo)
// Matches mfma_f32_16x16x32_f16 A/B layout: row/col = lane&15,
// k = (lane>>4)*8 + j. One qb = 128 queries = contiguous 128KB.

__global__ void vq_prep_z(const float* __restrict__ z, _Float16* __restrict__ zpk) {
  int t = blockIdx.x * 256 + threadIdx.x;    // 1,048,576 threads
  int l = t & 63, g = t >> 6;                // g = qb*64 + q16*8 + kk
  int qb = g >> 6, q16 = (g >> 3) & 7, kk = g & 7;
  int row = qb * 128 + q16 * 16 + (l & 15);
  int kc  = kk * 32 + (l >> 4) * 8;
  const float4* zp = (const float4*)(z + (size_t)row * 256 + kc);
  float4 a = zp[0], b = zp[1];
  float xs[8] = {a.x, a.y, a.z, a.w, b.x, b.y, b.z, b.w};
  half8 hh, ll;
#pragma unroll
  for (int j = 0; j < 8; ++j) {
    float x = xs[j] * 16.0f;
    _Float16 hj = (_Float16)x;
    hh[j] = hj; ll[j] = (_Float16)(x - (float)hj);
  }
  ((half8*)zpk)[(size_t)g * 128 + l]      = hh;
  ((half8*)zpk)[(size_t)g * 128 + 64 + l] = ll;
}

__global__ void vq_prep_e(const float* __restrict__ cb, _Float16* __restrict__ epk) {
  int t = blockIdx.x * 256 + threadIdx.x;    // 262,144 threads
  int l = t & 63, g = t >> 6;                // g = c16*8 + kk
  int c16 = g >> 3, kk = g & 7;
  int code = c16 * 16 + (l & 15);
  int kc   = kk * 32 + (l >> 4) * 8;
  const float4* ep = (const float4*)(cb + (size_t)code * 256 + kc);
  float4 a = ep[0], b = ep[1];
  float xs[8] = {a.x, a.y, a.z, a.w, b.x, b.y, b.z, b.w};
  half8 hh, ll;
#pragma unroll
  for (int j = 0; j < 8; ++j) {
    float x = xs[j] * 32768.0f;
    _Float16 hj = (_Float16)x;
    hh[j] = hj; ll[j] = (_Float16)(x - (float)hj);
  }
  ((half8*)epk)[(size_t)g * 128 + l]      = hh;
  ((half8*)epk)[(size_t)g * 128 + 64 + l] = ll;
}

// cbs[code] = 2^19 * ||e_code||^2  (unscaled sum, like reference)
__global__ void vq_prep_cbs(const float* __restrict__ cb, float* __restrict__ cbs) {
  int w = threadIdx.x >> 6, lane = threadIdx.x & 63;
  int code = blockIdx.x * 4 + w;             // wave per code
  float4 v = ((const float4*)cb)[code * 64 + lane];
  float ss = v.x * v.x + v.y * v.y + v.z * v.z + v.w * v.w;
#pragma unroll
  for (int off = 1; off < 64; off <<= 1) ss += __shfl_xor(ss, off);
  if (lane == 0) cbs[code] = ss * 524288.0f;
}

// ---------------- main: fused GEMM + running argmin ----------------
// Grid 256 blocks = 1/CU (LDS 128KB). Block = 1024 thr = 16 waves =
// 4/SIMD guaranteed (one workgroup's waves are co-resident). Wave
// (h,v,p): rows h*64..+64, cols v*64..+64 of ct = p*16+i, i in 0..16.
// No barriers in the main loop.
__global__ __launch_bounds__(1024, 4)
void vq_main(const _Float16* __restrict__ zpk, const _Float16* __restrict__ epk,
             const float* __restrict__ cbs, int* __restrict__ out) {
  __shared__ __align__(16) char smem[131072];   // A panel (128 q), frag-major
  _Float16* const A = (_Float16*)smem;

  const int tid  = threadIdx.x;
  const int lane = tid & 63;
  const int w    = tid >> 6;       // 0..15
  const int v    = w & 1;          // code-col half within ct
  const int p    = (w >> 1) & 3;   // ct quarter (16 cts each)
  const int h    = w >> 3;         // query-row half
  const int q    = lane & 15;
  const int quad = lane >> 4;
  const int b    = blockIdx.x;     // 128-query tile id
  const int q0   = b * 128;

  // Prologue: linear 128KB copy of this block's frag-major A panel.
  {
    const _Float16* src = zpk + (size_t)b * 65536;
    for (int c = 0; c < 8; ++c) {
      const int off = (c * 1024 + tid) * 8;    // f16 elems (16B/thread)
      gl_lds16(src + off, A + off);
    }
  }
  __syncthreads();   // drains vmcnt; A read-only from here on

  // A frags (LDS, half8 units): Ab[mt*1024 + kk*128 (+64 for lo)]
  const half8* const Ab = (const half8*)A + h * 4096 + lane;
  // B frags (global, half8 units): ebi[nt*1024 + kk*128 (+64 for lo)]
  const half8* const eb = (const half8*)epk + (size_t)v * 4096 + lane;

  float    rd[16];
  unsigned rc[16];
#pragma unroll
  for (int i = 0; i < 16; ++i) { rd[i] = 3.0e38f; rc[i] = 0u; }

  for (int i = 0; i < 16; ++i) {
    const int ct   = p * 16 + i;
    const int col0 = ct * 128 + v * 64 + q;
    const half8* const ebi = eb + (size_t)ct * 8192;

    float cbsv[4];
#pragma unroll
    for (int nt = 0; nt < 4; ++nt) cbsv[nt] = cbs[col0 + nt * 16];

    f32x4 acc[4][4];
#pragma unroll
    for (int mt = 0; mt < 4; ++mt)
#pragma unroll
      for (int nt = 0; nt < 4; ++nt)
        acc[mt][nt] = (f32x4){0.f, 0.f, 0.f, 0.f};

#pragma unroll 2
    for (int kk = 0; kk < 8; ++kk) {
      half8 bh[4], bl[4], ah[4], al[4];
#pragma unroll
      for (int nt = 0; nt < 4; ++nt) {
        bh[nt] = ebi[nt * 1024 + kk * 128];
        bl[nt] = ebi[nt * 1024 + kk * 128 + 64];
      }
#pragma unroll
      for (int mt = 0; mt < 4; ++mt) {
        ah[mt] = Ab[mt * 1024 + kk * 128];
        al[mt] = Ab[mt * 1024 + kk * 128 + 64];
      }
#pragma unroll
      for (int mt = 0; mt < 4; ++mt)
#pragma unroll
        for (int nt = 0; nt < 4; ++nt) {
          acc[mt][nt] = __builtin_amdgcn_mfma_f32_16x16x32_f16(ah[mt], bh[nt], acc[mt][nt], 0, 0, 0);
          acc[mt][nt] = __builtin_amdgcn_mfma_f32_16x16x32_f16(ah[mt], bl[nt], acc[mt][nt], 0, 0, 0);
          acc[mt][nt] = __builtin_amdgcn_mfma_f32_16x16x32_f16(al[mt], bh[nt], acc[mt][nt], 0, 0, 0);
        }
    }

    // dist = 2^19*cb_sq - 2*acc; running (min,idx). Explicit index
    // compare on ties -> order-independent lowest-index semantics.
#pragma unroll
    for (int mt = 0; mt < 4; ++mt)
#pragma unroll
      for (int r = 0; r < 4; ++r) {
        float d = fmaf(-2.0f, acc[mt][0][r], cbsv[0]);
        unsigned cidx = (unsigned)col0;
#pragma unroll
        for (int nt = 1; nt < 4; ++nt) {
          float dn = fmaf(-2.0f, acc[mt][nt][r], cbsv[nt]);
          if (dn < d) { d = dn; cidx = (unsigned)(col0 + nt * 16); }
        }
        int ri = mt * 4 + r;
        if (d < rd[ri]) { rd[ri] = d; rc[ri] = cidx; }
      }
  }

  // Reduce: 16-lane groups hold 16 cols of the same rows; then combine
  // the 8 (v,p) candidates per row via LDS (overlaying dead A region).
  __syncthreads();                       // all waves done reading A
  float*    const redD = (float*)smem;   // [8][128]
  unsigned* const redC = (unsigned*)(smem + 4096);

#pragma unroll
  for (int ri = 0; ri < 16; ++ri) {
    float d = rd[ri]; unsigned cidx = rc[ri];
#pragma unroll
    for (int off = 1; off < 16; off <<= 1) {
      float od = __shfl_xor(d, off);
      unsigned oc = __shfl_xor(cidx, off);
      if (od < d || (od == d && oc < cidx)) { d = od; cidx = oc; }
    }
    if (q == 0) {
      int row = h * 64 + (ri >> 2) * 16 + quad * 4 + (ri & 3);  // 0..127
      redD[(w & 7) * 128 + row] = d;
      redC[(w & 7) * 128 + row] = cidx;
    }
  }
  __syncthreads();
  if (tid < 128) {
    float d0 = redD[tid]; unsigned c0 = redC[tid];
#pragma unroll
    for (int s = 1; s < 8; ++s) {
      float ds = redD[s * 128 + tid]; unsigned cs = redC[s * 128 + tid];
      if (ds < d0 || (ds == d0 && cs < c0)) { d0 = ds; c0 = cs; }
    }
    out[q0 + tid] = (int)c0;
  }
}

extern "C" void kernel_launch(void* const* d_in, const int* in_sizes, int n_in,
                              void* d_out, int out_size, void* d_ws, size_t ws_size,
                              hipStream_t stream) {
  const float* z  = (const float*)d_in[0];   // [32,32,32,256] fp32
  const float* cb = (const float*)d_in[1];   // [8192,256] fp32
  char* ws = (char*)d_ws;
  // ws layout (~40 MB): zpk 32M (frag-major z hi/lo) | epk 8M | cbs 32K
  _Float16* zpk = (_Float16*)(ws);
  _Float16* epk = (_Float16*)(ws + (size_t)32 * 1024 * 1024);
  float*    cbs = (float*)(ws + (size_t)40 * 1024 * 1024);

  hipLaunchKernelGGL(vq_prep_z,   dim3(4096), dim3(256), 0, stream, z, zpk);
  hipLaunchKernelGGL(vq_prep_e,   dim3(1024), dim3(256), 0, stream, cb, epk);
  hipLaunchKernelGGL(vq_prep_cbs, dim3(2048), dim3(256), 0, stream, cb, cbs);
  hipLaunchKernelGGL(vq_main,     dim3(256),  dim3(1024), 0, stream,
                     zpk, epk, cbs, (int*)d_out);
}

// Round 10
// 502.188 us; speedup vs baseline: 1.0120x; 1.0120x over previous
//
#include <hip/hip_runtime.h>
#include <hip/hip_fp16.h>

// VQ codebook argmin: N=32768 queries x K=8192 codes x D=256 fp32.
// f16 hi/lo split (3 MFMA terms) => fp32-accurate dots on the matrix pipe;
// fused running argmin. Scaling (exact powers of 2, argmin-invariant):
// z*=2^4, e*=2^15; dist_scaled = 2^19*cb_sq - 2*acc.
//
// R10: R9 minus the VGPR cap. R9 proved the 1024-thr block gives 16
// co-resident waves = 4 waves/SIMD (Occupancy 22->45%) BUT its
// launch_bounds(1024,4) second arg made the allocator target a
// 64-VGPR (8 waves/SIMD) budget -> massive spill (WRITE 0.13MB->910MB,
// MfmaUtil 44%). The code needs ~96 regs (R7/R8 measured). For a
// 1024-thread block the backend must cap VGPR at 128 anyway (16 waves
// must fit: 4x128 = 512 = SIMD pool), so drop the second arg entirely.
// Everything else identical to R9.

#define N_Q   32768
#define K_CB  8192
#define D_DIM 256

typedef _Float16 half8 __attribute__((ext_vector_type(8)));
typedef float    f32x4 __attribute__((ext_vector_type(4)));

__device__ __forceinline__ void gl_lds16(const _Float16* g, _Float16* l) {
  __builtin_amdgcn_global_load_lds(
      (const __attribute__((address_space(1))) unsigned int*)g,
      (__attribute__((address_space(3))) unsigned int*)l, 16, 0, 0);
}

// Frag-major layouts (half8 index):
//   zpk: ((qb*64 + q16*8 + kk)*2 + hl)*64 + l
//        = z[qb*128 + q16*16 + (l&15)][kk*32 + (l>>4)*8 + j]  (*2^4, hi/lo)
//   epk: ((c16*8  + kk)*2 + hl)*64 + l
//        = e[c16*16 + (l&15)][kk*32 + (l>>4)*8 + j]           (*2^15, hi/lo)
// Matches mfma_f32_16x16x32_f16 A/B layout: row/col = lane&15,
// k = (lane>>4)*8 + j. One qb = 128 queries = contiguous 128KB.

__global__ void vq_prep_z(const float* __restrict__ z, _Float16* __restrict__ zpk) {
  int t = blockIdx.x * 256 + threadIdx.x;    // 1,048,576 threads
  int l = t & 63, g = t >> 6;                // g = qb*64 + q16*8 + kk
  int qb = g >> 6, q16 = (g >> 3) & 7, kk = g & 7;
  int row = qb * 128 + q16 * 16 + (l & 15);
  int kc  = kk * 32 + (l >> 4) * 8;
  const float4* zp = (const float4*)(z + (size_t)row * 256 + kc);
  float4 a = zp[0], b = zp[1];
  float xs[8] = {a.x, a.y, a.z, a.w, b.x, b.y, b.z, b.w};
  half8 hh, ll;
#pragma unroll
  for (int j = 0; j < 8; ++j) {
    float x = xs[j] * 16.0f;
    _Float16 hj = (_Float16)x;
    hh[j] = hj; ll[j] = (_Float16)(x - (float)hj);
  }
  ((half8*)zpk)[(size_t)g * 128 + l]      = hh;
  ((half8*)zpk)[(size_t)g * 128 + 64 + l] = ll;
}

__global__ void vq_prep_e(const float* __restrict__ cb, _Float16* __restrict__ epk) {
  int t = blockIdx.x * 256 + threadIdx.x;    // 262,144 threads
  int l = t & 63, g = t >> 6;                // g = c16*8 + kk
  int c16 = g >> 3, kk = g & 7;
  int code = c16 * 16 + (l & 15);
  int kc   = kk * 32 + (l >> 4) * 8;
  const float4* ep = (const float4*)(cb + (size_t)code * 256 + kc);
  float4 a = ep[0], b = ep[1];
  float xs[8] = {a.x, a.y, a.z, a.w, b.x, b.y, b.z, b.w};
  half8 hh, ll;
#pragma unroll
  for (int j = 0; j < 8; ++j) {
    float x = xs[j] * 32768.0f;
    _Float16 hj = (_Float16)x;
    hh[j] = hj; ll[j] = (_Float16)(x - (float)hj);
  }
  ((half8*)epk)[(size_t)g * 128 + l]      = hh;
  ((half8*)epk)[(size_t)g * 128 + 64 + l] = ll;
}

// cbs[code] = 2^19 * ||e_code||^2  (unscaled sum, like reference)
__global__ void vq_prep_cbs(const float* __restrict__ cb, float* __restrict__ cbs) {
  int w = threadIdx.x >> 6, lane = threadIdx.x & 63;
  int code = blockIdx.x * 4 + w;             // wave per code
  float4 v = ((const float4*)cb)[code * 64 + lane];
  float ss = v.x * v.x + v.y * v.y + v.z * v.z + v.w * v.w;
#pragma unroll
  for (int off = 1; off < 64; off <<= 1) ss += __shfl_xor(ss, off);
  if (lane == 0) cbs[code] = ss * 524288.0f;
}

// ---------------- main: fused GEMM + running argmin ----------------
// Grid 256 blocks = 1/CU (LDS 128KB). Block = 1024 thr = 16 waves =
// 4/SIMD guaranteed (one workgroup's waves are co-resident; backend
// caps VGPR at 128 so the block is schedulable). Wave (h,v,p): rows
// h*64..+64, cols v*64..+64 of ct = p*16+i, i in 0..16. No barriers
// in the main loop.
__global__ __launch_bounds__(1024)
void vq_main(const _Float16* __restrict__ zpk, const _Float16* __restrict__ epk,
             const float* __restrict__ cbs, int* __restrict__ out) {
  __shared__ __align__(16) char smem[131072];   // A panel (128 q), frag-major
  _Float16* const A = (_Float16*)smem;

  const int tid  = threadIdx.x;
  const int lane = tid & 63;
  const int w    = tid >> 6;       // 0..15
  const int v    = w & 1;          // code-col half within ct
  const int p    = (w >> 1) & 3;   // ct quarter (16 cts each)
  const int h    = w >> 3;         // query-row half
  const int q    = lane & 15;
  const int quad = lane >> 4;
  const int b    = blockIdx.x;     // 128-query tile id
  const int q0   = b * 128;

  // Prologue: linear 128KB copy of this block's frag-major A panel.
  {
    const _Float16* src = zpk + (size_t)b * 65536;
    for (int c = 0; c < 8; ++c) {
      const int off = (c * 1024 + tid) * 8;    // f16 elems (16B/thread)
      gl_lds16(src + off, A + off);
    }
  }
  __syncthreads();   // drains vmcnt; A read-only from here on

  // A frags (LDS, half8 units): Ab[mt*1024 + kk*128 (+64 for lo)]
  const half8* const Ab = (const half8*)A + h * 4096 + lane;
  // B frags (global, half8 units): ebi[nt*1024 + kk*128 (+64 for lo)]
  const half8* const eb = (const half8*)epk + (size_t)v * 4096 + lane;

  float    rd[16];
  unsigned rc[16];
#pragma unroll
  for (int i = 0; i < 16; ++i) { rd[i] = 3.0e38f; rc[i] = 0u; }

  for (int i = 0; i < 16; ++i) {
    const int ct   = p * 16 + i;
    const int col0 = ct * 128 + v * 64 + q;
    const half8* const ebi = eb + (size_t)ct * 8192;

    float cbsv[4];
#pragma unroll
    for (int nt = 0; nt < 4; ++nt) cbsv[nt] = cbs[col0 + nt * 16];

    f32x4 acc[4][4];
#pragma unroll
    for (int mt = 0; mt < 4; ++mt)
#pragma unroll
      for (int nt = 0; nt < 4; ++nt)
        acc[mt][nt] = (f32x4){0.f, 0.f, 0.f, 0.f};

#pragma unroll 2
    for (int kk = 0; kk < 8; ++kk) {
      half8 bh[4], bl[4], ah[4], al[4];
#pragma unroll
      for (int nt = 0; nt < 4; ++nt) {
        bh[nt] = ebi[nt * 1024 + kk * 128];
        bl[nt] = ebi[nt * 1024 + kk * 128 + 64];
      }
#pragma unroll
      for (int mt = 0; mt < 4; ++mt) {
        ah[mt] = Ab[mt * 1024 + kk * 128];
        al[mt] = Ab[mt * 1024 + kk * 128 + 64];
      }
#pragma unroll
      for (int mt = 0; mt < 4; ++mt)
#pragma unroll
        for (int nt = 0; nt < 4; ++nt) {
          acc[mt][nt] = __builtin_amdgcn_mfma_f32_16x16x32_f16(ah[mt], bh[nt], acc[mt][nt], 0, 0, 0);
          acc[mt][nt] = __builtin_amdgcn_mfma_f32_16x16x32_f16(ah[mt], bl[nt], acc[mt][nt], 0, 0, 0);
          acc[mt][nt] = __builtin_amdgcn_mfma_f32_16x16x32_f16(al[mt], bh[nt], acc[mt][nt], 0, 0, 0);
        }
    }

    // dist = 2^19*cb_sq - 2*acc; running (min,idx). Explicit index
    // compare on ties -> order-independent lowest-index semantics.
#pragma unroll
    for (int mt = 0; mt < 4; ++mt)
#pragma unroll
      for (int r = 0; r < 4; ++r) {
        float d = fmaf(-2.0f, acc[mt][0][r], cbsv[0]);
        unsigned cidx = (unsigned)col0;
#pragma unroll
        for (int nt = 1; nt < 4; ++nt) {
          float dn = fmaf(-2.0f, acc[mt][nt][r], cbsv[nt]);
          if (dn < d) { d = dn; cidx = (unsigned)(col0 + nt * 16); }
        }
        int ri = mt * 4 + r;
        if (d < rd[ri]) { rd[ri] = d; rc[ri] = cidx; }
      }
  }

  // Reduce: 16-lane groups hold 16 cols of the same rows; then combine
  // the 8 (v,p) candidates per row via LDS (overlaying dead A region).
  __syncthreads();                       // all waves done reading A
  float*    const redD = (float*)smem;   // [8][128]
  unsigned* const redC = (unsigned*)(smem + 4096);

#pragma unroll
  for (int ri = 0; ri < 16; ++ri) {
    float d = rd[ri]; unsigned cidx = rc[ri];
#pragma unroll
    for (int off = 1; off < 16; off <<= 1) {
      float od = __shfl_xor(d, off);
      unsigned oc = __shfl_xor(cidx, off);
      if (od < d || (od == d && oc < cidx)) { d = od; cidx = oc; }
    }
    if (q == 0) {
      int row = h * 64 + (ri >> 2) * 16 + quad * 4 + (ri & 3);  // 0..127
      redD[(w & 7) * 128 + row] = d;
      redC[(w & 7) * 128 + row] = cidx;
    }
  }
  __syncthreads();
  if (tid < 128) {
    float d0 = redD[tid]; unsigned c0 = redC[tid];
#pragma unroll
    for (int s = 1; s < 8; ++s) {
      float ds = redD[s * 128 + tid]; unsigned cs = redC[s * 128 + tid];
      if (ds < d0 || (ds == d0 && cs < c0)) { d0 = ds; c0 = cs; }
    }
    out[q0 + tid] = (int)c0;
  }
}

extern "C" void kernel_launch(void* const* d_in, const int* in_sizes, int n_in,
                              void* d_out, int out_size, void* d_ws, size_t ws_size,
                              hipStream_t stream) {
  const float* z  = (const float*)d_in[0];   // [32,32,32,256] fp32
  const float* cb = (const float*)d_in[1];   // [8192,256] fp32
  char* ws = (char*)d_ws;
  // ws layout (~40 MB): zpk 32M (frag-major z hi/lo) | epk 8M | cbs 32K
  _Float16* zpk = (_Float16*)(ws);
  _Float16* epk = (_Float16*)(ws + (size_t)32 * 1024 * 1024);
  float*    cbs = (float*)(ws + (size_t)40 * 1024 * 1024);

  hipLaunchKernelGGL(vq_prep_z,   dim3(4096), dim3(256), 0, stream, z, zpk);
  hipLaunchKernelGGL(vq_prep_e,   dim3(1024), dim3(256), 0, stream, cb, epk);
  hipLaunchKernelGGL(vq_prep_cbs, dim3(2048), dim3(256), 0, stream, cb, cbs);
  hipLaunchKernelGGL(vq_main,     dim3(256),  dim3(1024), 0, stream,
                     zpk, epk, cbs, (int*)d_out);
}

// Round 11
// 464.634 us; speedup vs baseline: 1.0938x; 1.0808x over previous
//
#include <hip/hip_runtime.h>
#include <hip/hip_fp16.h>

// VQ codebook argmin: N=32768 queries x K=8192 codes x D=256 fp32.
// f16 hi/lo split (3 MFMA terms) => fp32-accurate dots on the matrix pipe;
// fused running argmin. Scaling (exact powers of 2, argmin-invariant):
// z*=2^4, e*=2^15; dist_scaled = 2^19*cb_sq - 2*acc.
//
// R11: 32x32x16 MFMA ON THE R7 SKELETON. R9/R10 proved 4 waves/SIMD is
// structurally impossible for this tile (unified VGPR+AGPR file: 1024-thr
// block caps 128 regs/wave; acc alone is 64 -> unavoidable spill, WRITE
// 910MB). Frontier stays R7 (2 waves/SIMD, 63% MfmaUtil, 326us). Lever:
// shape. 32x32x16 = 33.8 cyc for 2x the FLOP of 16x16x32's 19.4 cyc
// (+15% rate, m06: 2382 vs 2075 TF) and HALF the MFMA instructions.
// Per-wave tile 64x64 = 2x2 of 32x32; acc f32x16[2][2] (64 regs, same).
// Operand map: row/col=lane&31, k=(lane>>5)*8+j. C map (m74/m101):
// col=lane&31, row=(r&3)+8*(r>>2)+4*(lane>>5). Per lane: 1 col x 16 rows
// per tile -> rd/rc[32], 5-step 32-lane shfl reduce. Rest identical: 256
// blocks x 512 thr, A-resident frag-major LDS, barrier-free B-from-L2.

#define N_Q   32768
#define K_CB  8192
#define D_DIM 256

typedef _Float16 half8 __attribute__((ext_vector_type(8)));
typedef float    f32x16 __attribute__((ext_vector_type(16)));

__device__ __forceinline__ void gl_lds16(const _Float16* g, _Float16* l) {
  __builtin_amdgcn_global_load_lds(
      (const __attribute__((address_space(1))) unsigned int*)g,
      (__attribute__((address_space(3))) unsigned int*)l, 16, 0, 0);
}

// Frag-major layouts (half8 index), 32x32x16 operand mapping
//   elem(row, k) with row = lane&31, k = kk*16 + (lane>>5)*8 + j:
//   zpk: ((qb*64 + q32*16 + kk)*2 + hl)*64 + l,  row = qb*128 + q32*32 + (l&31)
//   epk: ((c32*16 + kk)*2 + hl)*64 + l,          row = c32*32 + (l&31)
// qb: 128-query tile (contiguous 128KB); q32/c32: 32-row groups; kk: 0..15.

__global__ void vq_prep_z(const float* __restrict__ z, _Float16* __restrict__ zpk) {
  int t = blockIdx.x * 256 + threadIdx.x;    // 1,048,576 threads
  int l = t & 63, g = t >> 6;                // g = qb*64 + q32*16 + kk
  int qb = g >> 6, q32 = (g >> 4) & 3, kk = g & 15;
  int row = qb * 128 + q32 * 32 + (l & 31);
  int kc  = kk * 16 + (l >> 5) * 8;
  const float4* zp = (const float4*)(z + (size_t)row * 256 + kc);
  float4 a = zp[0], b = zp[1];
  float xs[8] = {a.x, a.y, a.z, a.w, b.x, b.y, b.z, b.w};
  half8 hh, ll;
#pragma unroll
  for (int j = 0; j < 8; ++j) {
    float x = xs[j] * 16.0f;
    _Float16 hj = (_Float16)x;
    hh[j] = hj; ll[j] = (_Float16)(x - (float)hj);
  }
  ((half8*)zpk)[(size_t)g * 128 + l]      = hh;
  ((half8*)zpk)[(size_t)g * 128 + 64 + l] = ll;
}

__global__ void vq_prep_e(const float* __restrict__ cb, _Float16* __restrict__ epk) {
  int t = blockIdx.x * 256 + threadIdx.x;    // 262,144 threads
  int l = t & 63, g = t >> 6;                // g = c32*16 + kk
  int c32 = g >> 4, kk = g & 15;
  int code = c32 * 32 + (l & 31);
  int kc   = kk * 16 + (l >> 5) * 8;
  const float4* ep = (const float4*)(cb + (size_t)code * 256 + kc);
  float4 a = ep[0], b = ep[1];
  float xs[8] = {a.x, a.y, a.z, a.w, b.x, b.y, b.z, b.w};
  half8 hh, ll;
#pragma unroll
  for (int j = 0; j < 8; ++j) {
    float x = xs[j] * 32768.0f;
    _Float16 hj = (_Float16)x;
    hh[j] = hj; ll[j] = (_Float16)(x - (float)hj);
  }
  ((half8*)epk)[(size_t)g * 128 + l]      = hh;
  ((half8*)epk)[(size_t)g * 128 + 64 + l] = ll;
}

// cbs[code] = 2^19 * ||e_code||^2  (unscaled sum, like reference)
__global__ void vq_prep_cbs(const float* __restrict__ cb, float* __restrict__ cbs) {
  int w = threadIdx.x >> 6, lane = threadIdx.x & 63;
  int code = blockIdx.x * 4 + w;             // wave per code
  float4 v = ((const float4*)cb)[code * 64 + lane];
  float ss = v.x * v.x + v.y * v.y + v.z * v.z + v.w * v.w;
#pragma unroll
  for (int off = 1; off < 64; off <<= 1) ss += __shfl_xor(ss, off);
  if (lane == 0) cbs[code] = ss * 524288.0f;
}

// ---------------- main: fused GEMM + running argmin ----------------
// Grid 256 blocks (1/CU, LDS 128KB). Block = 512 thr = 8 waves = 2/SIMD.
// Wave (h,v,p): rows h*64..+64, cols v*64..+64 of ct = p*32+i, i in 0..32.
// Per wave: 2x2 of 32x32 tiles, 16 k-steps of K=16. No main-loop barriers.
__global__ __launch_bounds__(512, 2)
void vq_main(const _Float16* __restrict__ zpk, const _Float16* __restrict__ epk,
             const float* __restrict__ cbs, int* __restrict__ out) {
  __shared__ __align__(16) char smem[131072];   // A panel (128 q), frag-major
  _Float16* const A = (_Float16*)smem;

  const int tid  = threadIdx.x;
  const int lane = tid & 63;
  const int w    = tid >> 6;       // 0..7
  const int v    = w & 1;          // code-col half within ct
  const int p    = (w >> 1) & 1;   // ct stream (0: cts 0..31, 1: 32..63)
  const int h    = w >> 2;         // query-row half
  const int c32l = lane & 31;      // col within a 32x32 tile
  const int hi   = lane >> 5;
  const int b    = blockIdx.x;     // 128-query tile id
  const int q0   = b * 128;

  // Prologue: linear 128KB copy of this block's frag-major A panel.
  {
    const _Float16* src = zpk + (size_t)b * 65536;
    for (int c = 0; c < 16; ++c) {
      const int off = (c * 512 + tid) * 8;     // f16 elems (16B/thread)
      gl_lds16(src + off, A + off);
    }
  }
  __syncthreads();   // drains vmcnt; A read-only from here on

  // A frags (LDS, half8): Ab[mt*2048 + kk*128 (+64 for lo)]
  const half8* const Ab = (const half8*)A + h * 4096 + lane;
  // B frags (global, half8): ebi[nt*2048 + kk*128 (+64 for lo)]
  const half8* const eb = (const half8*)epk + (size_t)v * 4096 + lane;

  float    rd[32];
  unsigned rc[32];
#pragma unroll
  for (int i = 0; i < 32; ++i) { rd[i] = 3.0e38f; rc[i] = 0u; }

  for (int i = 0; i < 32; ++i) {
    const int ct   = p * 32 + i;
    const int col0 = ct * 128 + v * 64 + c32l;      // this lane's col, nt=0
    const half8* const ebi = eb + (size_t)ct * 8192;

    float cbsv[2];
#pragma unroll
    for (int nt = 0; nt < 2; ++nt) cbsv[nt] = cbs[col0 + nt * 32];

    f32x16 acc[2][2];
#pragma unroll
    for (int mt = 0; mt < 2; ++mt)
#pragma unroll
      for (int nt = 0; nt < 2; ++nt)
        acc[mt][nt] = (f32x16)(0.0f);

#pragma unroll 2
    for (int kk = 0; kk < 16; ++kk) {
      half8 bh[2], bl[2], ah[2], al[2];
#pragma unroll
      for (int nt = 0; nt < 2; ++nt) {
        bh[nt] = ebi[nt * 2048 + kk * 128];
        bl[nt] = ebi[nt * 2048 + kk * 128 + 64];
      }
#pragma unroll
      for (int mt = 0; mt < 2; ++mt) {
        ah[mt] = Ab[mt * 2048 + kk * 128];
        al[mt] = Ab[mt * 2048 + kk * 128 + 64];
      }
#pragma unroll
      for (int mt = 0; mt < 2; ++mt)
#pragma unroll
        for (int nt = 0; nt < 2; ++nt) {
          acc[mt][nt] = __builtin_amdgcn_mfma_f32_32x32x16_f16(ah[mt], bh[nt], acc[mt][nt], 0, 0, 0);
          acc[mt][nt] = __builtin_amdgcn_mfma_f32_32x32x16_f16(ah[mt], bl[nt], acc[mt][nt], 0, 0, 0);
          acc[mt][nt] = __builtin_amdgcn_mfma_f32_32x32x16_f16(al[mt], bh[nt], acc[mt][nt], 0, 0, 0);
        }
    }

    // dist = 2^19*cb_sq - 2*acc; running (min,idx). C layout: this lane's
    // col = col0 + nt*32; reg r -> row (r&3)+8*(r>>2)+4*hi within the tile.
    // nt ascending = cols ascending, ct ascending -> strict < keeps the
    // lowest index on ties.
#pragma unroll
    for (int mt = 0; mt < 2; ++mt)
#pragma unroll
      for (int r = 0; r < 16; ++r) {
        float d = fmaf(-2.0f, acc[mt][0][r], cbsv[0]);
        unsigned cidx = (unsigned)col0;
        float dn = fmaf(-2.0f, acc[mt][1][r], cbsv[1]);
        if (dn < d) { d = dn; cidx = (unsigned)(col0 + 32); }
        int ri = mt * 16 + r;
        if (d < rd[ri]) { rd[ri] = d; rc[ri] = cidx; }
      }
  }

  // Reduce: each 32-lane half holds 32 cols of the same 16-row set per
  // (mt,r). 5-step shfl_xor min over cols; then combine the 4 (p,v)
  // slots per row via LDS (overlaying dead A region).
  __syncthreads();                       // all waves done reading A
  float*    const redD = (float*)smem;   // [4][128]
  unsigned* const redC = (unsigned*)(smem + 2048);

#pragma unroll
  for (int ri = 0; ri < 32; ++ri) {
    float d = rd[ri]; unsigned cidx = rc[ri];
#pragma unroll
    for (int off = 1; off < 32; off <<= 1) {
      float od = __shfl_xor(d, off);
      unsigned oc = __shfl_xor(cidx, off);
      if (od < d || (od == d && oc < cidx)) { d = od; cidx = oc; }
    }
    if (c32l == 0) {                     // lanes 0 and 32 write (hi=0/1 rows)
      int mt = ri >> 4, r = ri & 15;
      int row = h * 64 + mt * 32 + (r & 3) + 8 * (r >> 2) + 4 * hi;  // 0..127
      redD[(w & 3) * 128 + row] = d;
      redC[(w & 3) * 128 + row] = cidx;
    }
  }
  __syncthreads();
  if (tid < 128) {
    float d0 = redD[tid]; unsigned c0 = redC[tid];
#pragma unroll
    for (int s = 1; s < 4; ++s) {
      float ds = redD[s * 128 + tid]; unsigned cs = redC[s * 128 + tid];
      if (ds < d0 || (ds == d0 && cs < c0)) { d0 = ds; c0 = cs; }
    }
    out[q0 + tid] = (int)c0;
  }
}

extern "C" void kernel_launch(void* const* d_in, const int* in_sizes, int n_in,
                              void* d_out, int out_size, void* d_ws, size_t ws_size,
                              hipStream_t stream) {
  const float* z  = (const float*)d_in[0];   // [32,32,32,256] fp32
  const float* cb = (const float*)d_in[1];   // [8192,256] fp32
  char* ws = (char*)d_ws;
  // ws layout (~40 MB): zpk 32M (frag-major z hi/lo) | epk 8M | cbs 32K
  _Float16* zpk = (_Float16*)(ws);
  _Float16* epk = (_Float16*)(ws + (size_t)32 * 1024 * 1024);
  float*    cbs = (float*)(ws + (size_t)40 * 1024 * 1024);

  hipLaunchKernelGGL(vq_prep_z,   dim3(4096), dim3(256), 0, stream, z, zpk);
  hipLaunchKernelGGL(vq_prep_e,   dim3(1024), dim3(256), 0, stream, cb, epk);
  hipLaunchKernelGGL(vq_prep_cbs, dim3(2048), dim3(256), 0, stream, cb, cbs);
  hipLaunchKernelGGL(vq_main,     dim3(256),  dim3(512), 0, stream,
                     zpk, epk, cbs, (int*)d_out);
}

// Round 13
// 457.088 us; speedup vs baseline: 1.1118x; 1.0165x over previous
//
#include <hip/hip_runtime.h>
#include <hip/hip_fp16.h>

// VQ codebook argmin: N=32768 queries x K=8192 codes x D=256 fp32.
// f16 hi/lo split (3 MFMA terms) => fp32-accurate dots on the matrix pipe;
// fused running argmin. Scaling (exact powers of 2, argmin-invariant):
// z*=2^4, e*=2^15; dist_scaled = 2^19*cb_sq - 2*acc.
//
// R12/R13: 3 WAVES/SIMD. R11's 32x32 shape regressed (4 indep MFMA chains
// can't feed the pipe; reverted to 16x16x32 4x4). R9/R10: 16-wave blocks
// (4/SIMD) cap regs at 128 -> structural spill. But a 768-thr block
// (12 waves) forces only 3/SIMD -> cap ~170; R7's footprint is 92 arch
// + 64 acc = 156 <= 170: fits. One extra sibling wave per SIMD to hide
// B-load latency + VALU epilogue under MFMA. Rest = R7 verbatim
// (A-resident 128KB frag-major LDS, barrier-free B-from-L2 main loop).
// Wave (h,v,p): row-half x col-half x ct-third (21/21/22).
// (R12 bench was an infra failure - container acquisition; resubmitted.)

#define N_Q   32768
#define K_CB  8192
#define D_DIM 256

typedef _Float16 half8 __attribute__((ext_vector_type(8)));
typedef float    f32x4 __attribute__((ext_vector_type(4)));

__device__ __forceinline__ void gl_lds16(const _Float16* g, _Float16* l) {
  __builtin_amdgcn_global_load_lds(
      (const __attribute__((address_space(1))) unsigned int*)g,
      (__attribute__((address_space(3))) unsigned int*)l, 16, 0, 0);
}

// Frag-major layouts (half8 index):
//   zpk: ((qb*64 + q16*8 + kk)*2 + hl)*64 + l
//        = z[qb*128 + q16*16 + (l&15)][kk*32 + (l>>4)*8 + j]  (*2^4, hi/lo)
//   epk: ((c16*8  + kk)*2 + hl)*64 + l
//        = e[c16*16 + (l&15)][kk*32 + (l>>4)*8 + j]           (*2^15, hi/lo)
// Matches mfma_f32_16x16x32_f16 A/B layout: row/col = lane&15,
// k = (lane>>4)*8 + j. One qb = 128 queries = contiguous 128KB.

__global__ void vq_prep_z(const float* __restrict__ z, _Float16* __restrict__ zpk) {
  int t = blockIdx.x * 256 + threadIdx.x;    // 1,048,576 threads
  int l = t & 63, g = t >> 6;                // g = qb*64 + q16*8 + kk
  int qb = g >> 6, q16 = (g >> 3) & 7, kk = g & 7;
  int row = qb * 128 + q16 * 16 + (l & 15);
  int kc  = kk * 32 + (l >> 4) * 8;
  const float4* zp = (const float4*)(z + (size_t)row * 256 + kc);
  float4 a = zp[0], b = zp[1];
  float xs[8] = {a.x, a.y, a.z, a.w, b.x, b.y, b.z, b.w};
  half8 hh, ll;
#pragma unroll
  for (int j = 0; j < 8; ++j) {
    float x = xs[j] * 16.0f;
    _Float16 hj = (_Float16)x;
    hh[j] = hj; ll[j] = (_Float16)(x - (float)hj);
  }
  ((half8*)zpk)[(size_t)g * 128 + l]      = hh;
  ((half8*)zpk)[(size_t)g * 128 + 64 + l] = ll;
}

__global__ void vq_prep_e(const float* __restrict__ cb, _Float16* __restrict__ epk) {
  int t = blockIdx.x * 256 + threadIdx.x;    // 262,144 threads
  int l = t & 63, g = t >> 6;                // g = c16*8 + kk
  int c16 = g >> 3, kk = g & 7;
  int code = c16 * 16 + (l & 15);
  int kc   = kk * 32 + (l >> 4) * 8;
  const float4* ep = (const float4*)(cb + (size_t)code * 256 + kc);
  float4 a = ep[0], b = ep[1];
  float xs[8] = {a.x, a.y, a.z, a.w, b.x, b.y, b.z, b.w};
  half8 hh, ll;
#pragma unroll
  for (int j = 0; j < 8; ++j) {
    float x = xs[j] * 32768.0f;
    _Float16 hj = (_Float16)x;
    hh[j] = hj; ll[j] = (_Float16)(x - (float)hj);
  }
  ((half8*)epk)[(size_t)g * 128 + l]      = hh;
  ((half8*)epk)[(size_t)g * 128 + 64 + l] = ll;
}

// cbs[code] = 2^19 * ||e_code||^2  (unscaled sum, like reference)
__global__ void vq_prep_cbs(const float* __restrict__ cb, float* __restrict__ cbs) {
  int w = threadIdx.x >> 6, lane = threadIdx.x & 63;
  int code = blockIdx.x * 4 + w;             // wave per code
  float4 v = ((const float4*)cb)[code * 64 + lane];
  float ss = v.x * v.x + v.y * v.y + v.z * v.z + v.w * v.w;
#pragma unroll
  for (int off = 1; off < 64; off <<= 1) ss += __shfl_xor(ss, off);
  if (lane == 0) cbs[code] = ss * 524288.0f;
}

// ---------------- main: fused GEMM + running argmin ----------------
// Grid 256 blocks = 1/CU (LDS 128KB). Block = 768 thr = 12 waves =
// 3/SIMD co-resident (reg cap ~170 >= our 156). Wave (h,v,p): rows
// h*64..+64, cols v*64..+64 of cts [p*64/3, (p+1)*64/3). No barriers
// in the main loop.
__global__ __launch_bounds__(768, 3)
void vq_main(const _Float16* __restrict__ zpk, const _Float16* __restrict__ epk,
             const float* __restrict__ cbs, int* __restrict__ out) {
  __shared__ __align__(16) char smem[131072];   // A panel (128 q), frag-major
  _Float16* const A = (_Float16*)smem;

  const int tid  = threadIdx.x;
  const int lane = tid & 63;
  const int w    = tid >> 6;       // 0..11
  const int h    = w / 6;          // query-row half
  const int wr   = w % 6;          // 0..5
  const int p    = wr >> 1;        // ct third
  const int v    = wr & 1;         // code-col half
  const int q    = lane & 15;
  const int quad = lane >> 4;
  const int b    = blockIdx.x;     // 128-query tile id
  const int q0   = b * 128;

  // Prologue: linear 128KB copy of this block's frag-major A panel.
  // 8192 half8 slots over 768 threads: 11 iters, tail guard cuts whole
  // waves (8192 = 768*10 + 512; 512 = 8 full waves), exec-masked waves
  // issue nothing.
  {
    const _Float16* src = zpk + (size_t)b * 65536;
    for (int c = 0; c < 11; ++c) {
      const int idx = c * 768 + tid;
      if (idx < 8192) gl_lds16(src + idx * 8, A + idx * 8);
    }
  }
  __syncthreads();   // drains vmcnt; A read-only from here on

  // A frags (LDS, half8 units): Ab[mt*1024 + kk*128 (+64 for lo)]
  const half8* const Ab = (const half8*)A + h * 4096 + lane;
  // B frags (global, half8 units): ebi[nt*1024 + kk*128 (+64 for lo)]
  const half8* const eb = (const half8*)epk + (size_t)v * 4096 + lane;

  float    rd[16];
  unsigned rc[16];
#pragma unroll
  for (int i = 0; i < 16; ++i) { rd[i] = 3.0e38f; rc[i] = 0u; }

  const int cts = (p * 64) / 3;          // 0, 21, 42
  const int cte = ((p + 1) * 64) / 3;    // 21, 42, 64

  for (int ct = cts; ct < cte; ++ct) {
    const int col0 = ct * 128 + v * 64 + q;
    const half8* const ebi = eb + (size_t)ct * 8192;

    float cbsv[4];
#pragma unroll
    for (int nt = 0; nt < 4; ++nt) cbsv[nt] = cbs[col0 + nt * 16];

    f32x4 acc[4][4];
#pragma unroll
    for (int mt = 0; mt < 4; ++mt)
#pragma unroll
      for (int nt = 0; nt < 4; ++nt)
        acc[mt][nt] = (f32x4){0.f, 0.f, 0.f, 0.f};

#pragma unroll 2
    for (int kk = 0; kk < 8; ++kk) {
      half8 bh[4], bl[4], ah[4], al[4];
#pragma unroll
      for (int nt = 0; nt < 4; ++nt) {
        bh[nt] = ebi[nt * 1024 + kk * 128];
        bl[nt] = ebi[nt * 1024 + kk * 128 + 64];
      }
#pragma unroll
      for (int mt = 0; mt < 4; ++mt) {
        ah[mt] = Ab[mt * 1024 + kk * 128];
        al[mt] = Ab[mt * 1024 + kk * 128 + 64];
      }
#pragma unroll
      for (int mt = 0; mt < 4; ++mt)
#pragma unroll
        for (int nt = 0; nt < 4; ++nt) {
          acc[mt][nt] = __builtin_amdgcn_mfma_f32_16x16x32_f16(ah[mt], bh[nt], acc[mt][nt], 0, 0, 0);
          acc[mt][nt] = __builtin_amdgcn_mfma_f32_16x16x32_f16(ah[mt], bl[nt], acc[mt][nt], 0, 0, 0);
          acc[mt][nt] = __builtin_amdgcn_mfma_f32_16x16x32_f16(al[mt], bh[nt], acc[mt][nt], 0, 0, 0);
        }
    }

    // dist = 2^19*cb_sq - 2*acc; running (min,idx). Explicit index
    // compare on ties -> order-independent lowest-index semantics.
#pragma unroll
    for (int mt = 0; mt < 4; ++mt)
#pragma unroll
      for (int r = 0; r < 4; ++r) {
        float d = fmaf(-2.0f, acc[mt][0][r], cbsv[0]);
        unsigned cidx = (unsigned)col0;
#pragma unroll
        for (int nt = 1; nt < 4; ++nt) {
          float dn = fmaf(-2.0f, acc[mt][nt][r], cbsv[nt]);
          if (dn < d || (dn == d && (unsigned)(col0 + nt * 16) < cidx)) {
            d = dn; cidx = (unsigned)(col0 + nt * 16);
          }
        }
        int ri = mt * 4 + r;
        if (d < rd[ri] || (d == rd[ri] && cidx < rc[ri])) { rd[ri] = d; rc[ri] = cidx; }
      }
  }

  // Reduce: 16-lane groups hold 16 cols of the same rows; then combine
  // the 6 (p,v) candidates per row via LDS (overlaying dead A region).
  __syncthreads();                       // all waves done reading A
  float*    const redD = (float*)smem;   // [6][128]
  unsigned* const redC = (unsigned*)(smem + 3072);

#pragma unroll
  for (int ri = 0; ri < 16; ++ri) {
    float d = rd[ri]; unsigned cidx = rc[ri];
#pragma unroll
    for (int off = 1; off < 16; off <<= 1) {
      float od = __shfl_xor(d, off);
      unsigned oc = __shfl_xor(cidx, off);
      if (od < d || (od == d && oc < cidx)) { d = od; cidx = oc; }
    }
    if (q == 0) {
      int row = h * 64 + (ri >> 2) * 16 + quad * 4 + (ri & 3);  // 0..127
      redD[wr * 128 + row] = d;
      redC[wr * 128 + row] = cidx;
    }
  }
  __syncthreads();
  if (tid < 128) {
    float d0 = redD[tid]; unsigned c0 = redC[tid];
#pragma unroll
    for (int s = 1; s < 6; ++s) {
      float ds = redD[s * 128 + tid]; unsigned cs = redC[s * 128 + tid];
      if (ds < d0 || (ds == d0 && cs < c0)) { d0 = ds; c0 = cs; }
    }
    out[q0 + tid] = (int)c0;
  }
}

extern "C" void kernel_launch(void* const* d_in, const int* in_sizes, int n_in,
                              void* d_out, int out_size, void* d_ws, size_t ws_size,
                              hipStream_t stream) {
  const float* z  = (const float*)d_in[0];   // [32,32,32,256] fp32
  const float* cb = (const float*)d_in[1];   // [8192,256] fp32
  char* ws = (char*)d_ws;
  // ws layout (~40 MB): zpk 32M (frag-major z hi/lo) | epk 8M | cbs 32K
  _Float16* zpk = (_Float16*)(ws);
  _Float16* epk = (_Float16*)(ws + (size_t)32 * 1024 * 1024);
  float*    cbs = (float*)(ws + (size_t)40 * 1024 * 1024);

  hipLaunchKernelGGL(vq_prep_z,   dim3(4096), dim3(256), 0, stream, z, zpk);
  hipLaunchKernelGGL(vq_prep_e,   dim3(1024), dim3(256), 0, stream, cb, epk);
  hipLaunchKernelGGL(vq_prep_cbs, dim3(2048), dim3(256), 0, stream, cb, cbs);
  hipLaunchKernelGGL(vq_main,     dim3(256),  dim3(768), 0, stream,
                     zpk, epk, cbs, (int*)d_out);
}

// Round 14
// 393.368 us; speedup vs baseline: 1.2920x; 1.1620x over previous
//
#include <hip/hip_runtime.h>
#include <hip/hip_fp16.h>

// VQ codebook argmin: N=32768 queries x K=8192 codes x D=256 fp32.
// f16 hi/lo split (3 MFMA terms) => fp32-accurate dots on the matrix pipe;
// fused running argmin. Scaling (exact powers of 2, argmin-invariant):
// z*=2^4, e*=2^15; dist_scaled = 2^19*cb_sq - 2*acc.
//
// R14: OPTIMIZE THE PREP PIPELINE, FREEZE vq_main. R8-R13 closed the
// occupancy arc: the 64-reg-acc tile spills beyond 2 waves/SIMD (R13 at
// 3/SIMD: 84 VGPR + 85MB scratch, MfmaUtil 47% < R7's 63%). R7's main
// (326us) is the structural optimum; but total = 400.9us -> preps +
// launch gaps = 75us for ~18us of ideal memory work. Old preps did
// frag-major GATHER reads (lanes at 1KB stride = 16-way uncoalesced on
// 33MB) across 3 launches. New: ONE fused prep kernel; each block
// stages 16 rows x 256 cols through padded LDS (stride 264 -> aligned
// 16B, <=4-way read conflicts), fully coalesced global read AND write;
// cbs row-sums fused into the codebook blocks. Grid 2560 = 2048 z +
// 512 e blocks. vq_main byte-identical to R7.

#define N_Q   32768
#define K_CB  8192
#define D_DIM 256

typedef _Float16 half8 __attribute__((ext_vector_type(8)));
typedef float    f32x4 __attribute__((ext_vector_type(4)));

__device__ __forceinline__ void gl_lds16(const _Float16* g, _Float16* l) {
  __builtin_amdgcn_global_load_lds(
      (const __attribute__((address_space(1))) unsigned int*)g,
      (__attribute__((address_space(3))) unsigned int*)l, 16, 0, 0);
}

// Frag-major layouts (half8 index):
//   zpk: ((qb*64 + q16*8 + kk)*2 + hl)*64 + l
//        = z[qb*128 + q16*16 + (l&15)][kk*32 + (l>>4)*8 + j]  (*2^4, hi/lo)
//   epk: ((c16*8  + kk)*2 + hl)*64 + l
//        = e[c16*16 + (l&15)][kk*32 + (l>>4)*8 + j]           (*2^15, hi/lo)
// Matches mfma_f32_16x16x32_f16 A/B layout: row/col = lane&15,
// k = (lane>>4)*8 + j. Per 16-row group the 1024 output half8s are
// contiguous: out[o], o = kk*128 + hl*64 + l.

// ---------------- fused prep: z and e (+cbs), coalesced both ways ----------
// Block = 256 thr <-> one 16-row x 256-col group. Blocks 0..2047: z
// (scale 2^4); blocks 2048..2559: codebook (scale 2^15, + cbs sums).
__global__ __launch_bounds__(256)
void vq_prep(const float* __restrict__ z, const float* __restrict__ cb,
             _Float16* __restrict__ zpk, _Float16* __restrict__ epk,
             float* __restrict__ cbs) {
  __shared__ float ld[16 * 264];          // padded: row stride 264 floats
  const int  t   = threadIdx.x;
  const bool isZ = (blockIdx.x < 2048);
  const int  blk = isZ ? blockIdx.x : (blockIdx.x - 2048);
  const float* src  = (isZ ? z : cb) + (size_t)blk * 4096;
  const float scale = isZ ? 16.0f : 32768.0f;
  _Float16*   dst   = (isZ ? zpk : epk) + (size_t)blk * 8192;

  // Stage 16x256 floats, coalesced: consecutive t -> consecutive float4.
#pragma unroll
  for (int c = 0; c < 4; ++c) {
    const int f   = c * 256 + t;          // float4 index 0..1023
    const int row = f >> 6, c4 = f & 63;
    float4 v = ((const float4*)src)[f];
    *(float4*)&ld[row * 264 + c4 * 4] = v;   // 264*4=1056 B stride (16B-aligned)
  }
  __syncthreads();

  // cbs for codebook blocks: 16 threads per code, shfl-reduce.
  if (!isZ) {
    const int ci = t >> 4, seg = t & 15;
    float s = 0.f;
#pragma unroll
    for (int j = 0; j < 16; ++j) {
      float x = ld[ci * 264 + seg * 16 + j];
      s = fmaf(x, x, s);
    }
#pragma unroll
    for (int off = 1; off < 16; off <<= 1) s += __shfl_xor(s, off);
    if (seg == 0) cbs[blk * 16 + ci] = s * 524288.0f;   // 2^19 * ||e||^2
  }

  // Convert + write frag-major, coalesced: consecutive t -> consecutive half8.
#pragma unroll
  for (int c = 0; c < 4; ++c) {
    const int o    = c * 256 + t;         // half8 out index 0..1023
    const int kk   = o >> 7, r = o & 127, hl = r >> 6, l = r & 63;
    const int lrow = l & 15, k0 = kk * 32 + (l >> 4) * 8;
    half8 hv;
#pragma unroll
    for (int j = 0; j < 8; ++j) {
      float x = ld[lrow * 264 + k0 + j] * scale;
      _Float16 hj = (_Float16)x;
      hv[j] = hl ? (_Float16)(x - (float)hj) : hj;
    }
    ((half8*)dst)[o] = hv;
  }
}

// ---------------- main: fused GEMM + running argmin (R7, frozen) ----------
// Grid 256 blocks (1/CU: LDS 128KB). Block = 512 thr = 8 waves = 2/SIMD.
// Wave (h,v,p): rows h*64..+64 of the block's 128 queries, cols v*64..+64
// of ct = p*32+i for i in 0..32. No barriers in the main loop.
__global__ __launch_bounds__(512, 2)
void vq_main(const _Float16* __restrict__ zpk, const _Float16* __restrict__ epk,
             const float* __restrict__ cbs, int* __restrict__ out) {
  __shared__ __align__(16) char smem[131072];   // A panel, frag-major
  _Float16* const A = (_Float16*)smem;

  const int tid  = threadIdx.x;
  const int lane = tid & 63;
  const int w    = tid >> 6;       // 0..7
  const int h    = w >> 2;         // query-row half
  const int v    = w & 1;          // code-col half
  const int p    = (w >> 1) & 1;   // ct stream (0: cts 0..31, 1: 32..63)
  const int q    = lane & 15;
  const int quad = lane >> 4;
  const int qb   = blockIdx.x;
  const int q0   = qb * 128;

  // Prologue: linear 128KB copy of this block's frag-major A panel.
  {
    const _Float16* src = zpk + (size_t)qb * 65536;
    for (int c = 0; c < 16; ++c) {
      const int off = (c * 512 + tid) * 8;     // f16 elems (16B/thread)
      gl_lds16(src + off, A + off);
    }
  }
  __syncthreads();   // drains vmcnt; A read-only from here on

  // A frags (LDS, half8 units): Ab[mt*1024 + kk*128 (+64 for lo)]
  const half8* const Ab = (const half8*)A + h * 4096 + lane;
  // B frags (global, half8 units): ebi[nt*1024 + kk*128 (+64 for lo)]
  const half8* const eb = (const half8*)epk + (size_t)v * 4096 + lane;

  float    rd[16];
  unsigned rc[16];
#pragma unroll
  for (int i = 0; i < 16; ++i) { rd[i] = 3.0e38f; rc[i] = 0u; }

  for (int i = 0; i < 32; ++i) {
    const int ct   = p * 32 + i;
    const int col0 = ct * 128 + v * 64 + q;
    const half8* const ebi = eb + (size_t)ct * 8192;

    float cbsv[4];
#pragma unroll
    for (int nt = 0; nt < 4; ++nt) cbsv[nt] = cbs[col0 + nt * 16];

    f32x4 acc[4][4];
#pragma unroll
    for (int mt = 0; mt < 4; ++mt)
#pragma unroll
      for (int nt = 0; nt < 4; ++nt)
        acc[mt][nt] = (f32x4){0.f, 0.f, 0.f, 0.f};

#pragma unroll 2
    for (int kk = 0; kk < 8; ++kk) {
      half8 bh[4], bl[4], ah[4], al[4];
#pragma unroll
      for (int nt = 0; nt < 4; ++nt) {
        bh[nt] = ebi[nt * 1024 + kk * 128];
        bl[nt] = ebi[nt * 1024 + kk * 128 + 64];
      }
#pragma unroll
      for (int mt = 0; mt < 4; ++mt) {
        ah[mt] = Ab[mt * 1024 + kk * 128];
        al[mt] = Ab[mt * 1024 + kk * 128 + 64];
      }
#pragma unroll
      for (int mt = 0; mt < 4; ++mt)
#pragma unroll
        for (int nt = 0; nt < 4; ++nt) {
          acc[mt][nt] = __builtin_amdgcn_mfma_f32_16x16x32_f16(ah[mt], bh[nt], acc[mt][nt], 0, 0, 0);
          acc[mt][nt] = __builtin_amdgcn_mfma_f32_16x16x32_f16(ah[mt], bl[nt], acc[mt][nt], 0, 0, 0);
          acc[mt][nt] = __builtin_amdgcn_mfma_f32_16x16x32_f16(al[mt], bh[nt], acc[mt][nt], 0, 0, 0);
        }
    }

    // dist = 2^19*cb_sq - 2*acc; running (min,idx). Ascending nt / i =>
    // strict < keeps the lowest index on ties.
#pragma unroll
    for (int mt = 0; mt < 4; ++mt)
#pragma unroll
      for (int r = 0; r < 4; ++r) {
        float d = fmaf(-2.0f, acc[mt][0][r], cbsv[0]);
        unsigned cidx = (unsigned)col0;
#pragma unroll
        for (int nt = 1; nt < 4; ++nt) {
          float dn = fmaf(-2.0f, acc[mt][nt][r], cbsv[nt]);
          if (dn < d) { d = dn; cidx = (unsigned)(col0 + nt * 16); }
        }
        int ri = mt * 4 + r;
        if (d < rd[ri]) { rd[ri] = d; rc[ri] = cidx; }
      }
  }

  // Reduce: 16-lane groups hold 16 cols of the same rows; then combine the
  // 4 (v,p) candidates per row via LDS (overlaying dead A region).
  __syncthreads();                       // all waves done reading A
  float*    const redD = (float*)smem;   // [4][128]
  unsigned* const redC = (unsigned*)(smem + 2048);

#pragma unroll
  for (int ri = 0; ri < 16; ++ri) {
    float d = rd[ri]; unsigned cidx = rc[ri];
#pragma unroll
    for (int off = 1; off < 16; off <<= 1) {
      float od = __shfl_xor(d, off);
      unsigned oc = __shfl_xor(cidx, off);
      if (od < d || (od == d && oc < cidx)) { d = od; cidx = oc; }
    }
    if (q == 0) {
      int row = h * 64 + (ri >> 2) * 16 + quad * 4 + (ri & 3);
      redD[(w & 3) * 128 + row] = d;
      redC[(w & 3) * 128 + row] = cidx;
    }
  }
  __syncthreads();
  if (tid < 128) {
    float d0 = redD[tid]; unsigned c0 = redC[tid];
#pragma unroll
    for (int s = 1; s < 4; ++s) {
      float ds = redD[s * 128 + tid]; unsigned cs = redC[s * 128 + tid];
      if (ds < d0 || (ds == d0 && cs < c0)) { d0 = ds; c0 = cs; }
    }
    out[q0 + tid] = (int)c0;
  }
}

extern "C" void kernel_launch(void* const* d_in, const int* in_sizes, int n_in,
                              void* d_out, int out_size, void* d_ws, size_t ws_size,
                              hipStream_t stream) {
  const float* z  = (const float*)d_in[0];   // [32,32,32,256] fp32
  const float* cb = (const float*)d_in[1];   // [8192,256] fp32
  char* ws = (char*)d_ws;
  // ws layout (~40 MB): zpk 32M (frag-major z hi/lo) | epk 8M | cbs 32K
  _Float16* zpk = (_Float16*)(ws);
  _Float16* epk = (_Float16*)(ws + (size_t)32 * 1024 * 1024);
  float*    cbs = (float*)(ws + (size_t)40 * 1024 * 1024);

  hipLaunchKernelGGL(vq_prep, dim3(2560), dim3(256), 0, stream,
                     z, cb, zpk, epk, cbs);
  hipLaunchKernelGGL(vq_main, dim3(256),  dim3(512), 0, stream,
                     zpk, epk, cbs, (int*)d_out);
}

// Round 15
// 385.701 us; speedup vs baseline: 1.3176x; 1.0199x over previous
//
#include <hip/hip_runtime.h>
#include <hip/hip_fp16.h>

// VQ codebook argmin: N=32768 queries x K=8192 codes x D=256 fp32.
// f16 hi/lo split (3 MFMA terms) => fp32-accurate dots on the matrix pipe;
// fused running argmin. Scaling (exact powers of 2, argmin-invariant):
// z*=2^4, e*=2^15; dist_scaled = 2^19*cb_sq - 2*acc.
//
// R15: KILL THE A-SIDE PREP ENTIRELY. R14's prep was still ~55us: its
// padded-LDS transpose read was 16-way bank-conflicted (bank =
// 8*((lrow+quad)&3) -> 16 lanes/bank-group), and z->zpk round-trips
// 64MB through global for data each main block consumes privately.
// Now vq_main's prologue converts z f32 -> hi/lo f16 frag-major
// DIRECTLY into its LDS A panel (register-only: 16-rows x 128B-line
// global reads, lane-linear conflict-free ds_write_b128). zpk deleted.
// Only remaining prep: tiny B-side kernel (cb -> epk frag-major + cbs,
// register-only, coalesced both ways, ~5us). Main loop byte-identical
// to R14 (321us, MfmaUtil 63%, the R7 frozen structure).

#define N_Q   32768
#define K_CB  8192
#define D_DIM 256

typedef _Float16 half8 __attribute__((ext_vector_type(8)));
typedef float    f32x4 __attribute__((ext_vector_type(4)));

// Frag-major epk layout (half8 index):
//   epk: ((c16*8 + kk)*2 + hl)*64 + l
//        = e[c16*16 + (l&15)][kk*32 + (l>>4)*8 + j]   (*2^15, hi/lo)
// Matches mfma_f32_16x16x32_f16 A/B layout: row/col = lane&15,
// k = (lane>>4)*8 + j.

// ---------------- prep: codebook -> epk frag-major + cbs ----------------
// One block per c16 (16 codes); 512 blocks x 256 thr. Register-only.
__global__ __launch_bounds__(256)
void vq_prep_e(const float* __restrict__ cb, _Float16* __restrict__ epk,
               float* __restrict__ cbs) {
  const int t = threadIdx.x, c16 = blockIdx.x;

  // Frag-major conversion: 512 (kk,l) pairs, 2 iters of 256 threads.
  // Global reads: per wave 16 rows x 128B contiguous (full cache lines).
  // Global writes: consecutive l -> consecutive 16B (coalesced dwordx4).
#pragma unroll
  for (int it = 0; it < 2; ++it) {
    const int s   = it * 256 + t;         // 0..511
    const int kk  = s >> 6, l = s & 63;
    const int row = c16 * 16 + (l & 15);
    const int k0  = kk * 32 + (l >> 4) * 8;
    const float4* ep = (const float4*)(cb + (size_t)row * 256 + k0);
    float4 a = ep[0], b = ep[1];
    float xs[8] = {a.x, a.y, a.z, a.w, b.x, b.y, b.z, b.w};
    half8 hh, ll;
#pragma unroll
    for (int j = 0; j < 8; ++j) {
      float x = xs[j] * 32768.0f;
      _Float16 hj = (_Float16)x;
      hh[j] = hj; ll[j] = (_Float16)(x - (float)hj);
    }
    half8* outg = (half8*)epk + (size_t)(c16 * 8 + kk) * 128;
    outg[l]      = hh;
    outg[64 + l] = ll;
  }

  // cbs: 16 codes x 16 threads; seg is the low 4 lane bits -> shfl group.
  {
    const int ci = t >> 4, seg = t & 15;
    const int row = c16 * 16 + ci;
    const float4* ep = (const float4*)(cb + (size_t)row * 256 + seg * 16);
    float s = 0.f;
#pragma unroll
    for (int u = 0; u < 4; ++u) {
      float4 v = ep[u];
      s = fmaf(v.x, v.x, fmaf(v.y, v.y, fmaf(v.z, v.z, fmaf(v.w, v.w, s))));
    }
#pragma unroll
    for (int off = 1; off < 16; off <<= 1) s += __shfl_xor(s, off);
    if (seg == 0) cbs[row] = s * 524288.0f;   // 2^19 * ||e||^2
  }
}

// ---------------- main: fused GEMM + running argmin ----------------
// Grid 256 blocks (1/CU: LDS 128KB). Block = 512 thr = 8 waves = 2/SIMD.
// Prologue converts this block's 128 z-rows f32 -> frag-major hi/lo A
// panel in LDS directly. Wave (h,v,p): rows h*64..+64, cols v*64..+64
// of ct = p*32+i for i in 0..32. No barriers in the main loop.
__global__ __launch_bounds__(512, 2)
void vq_main(const float* __restrict__ z, const _Float16* __restrict__ epk,
             const float* __restrict__ cbs, int* __restrict__ out) {
  __shared__ __align__(16) char smem[131072];   // A panel, frag-major
  _Float16* const A = (_Float16*)smem;

  const int tid  = threadIdx.x;
  const int lane = tid & 63;
  const int w    = tid >> 6;       // 0..7
  const int h    = w >> 2;         // query-row half
  const int v    = w & 1;          // code-col half
  const int p    = (w >> 1) & 1;   // ct stream (0: cts 0..31, 1: 32..63)
  const int q    = lane & 15;
  const int quad = lane >> 4;
  const int qb   = blockIdx.x;
  const int q0   = qb * 128;

  // Prologue: z[q0..q0+128) f32 -> hi/lo f16 frag-major A (reg-only).
  // A half8 layout: [g*128 + hl*64 + l], g = q16*8 + kk (identical to
  // the old zpk block image). Per wave-iter: g uniform, l = lane ->
  // global reads = 16 rows x 128B lines; LDS writes lane-linear 16B.
  {
    const float* zsrc = z + (size_t)q0 * 256;
#pragma unroll
    for (int it = 0; it < 8; ++it) {
      const int s   = it * 512 + tid;       // 0..4095
      const int g   = s >> 6, l = s & 63;   // g = q16*8 + kk
      const int row = (g >> 3) * 16 + (l & 15);
      const int k0  = (g & 7) * 32 + (l >> 4) * 8;
      const float4* zp = (const float4*)(zsrc + (size_t)row * 256 + k0);
      float4 a = zp[0], b = zp[1];
      float xs[8] = {a.x, a.y, a.z, a.w, b.x, b.y, b.z, b.w};
      half8 hh, ll;
#pragma unroll
      for (int j = 0; j < 8; ++j) {
        float x = xs[j] * 16.0f;
        _Float16 hj = (_Float16)x;
        hh[j] = hj; ll[j] = (_Float16)(x - (float)hj);
      }
      half8* const Ag = (half8*)A + g * 128;
      Ag[l]      = hh;
      Ag[64 + l] = ll;
    }
  }
  __syncthreads();   // A panel complete; read-only from here on

  // A frags (LDS, half8 units): Ab[mt*1024 + kk*128 (+64 for lo)]
  const half8* const Ab = (const half8*)A + h * 4096 + lane;
  // B frags (global, half8 units): ebi[nt*1024 + kk*128 (+64 for lo)]
  const half8* const eb = (const half8*)epk + (size_t)v * 4096 + lane;

  float    rd[16];
  unsigned rc[16];
#pragma unroll
  for (int i = 0; i < 16; ++i) { rd[i] = 3.0e38f; rc[i] = 0u; }

  for (int i = 0; i < 32; ++i) {
    const int ct   = p * 32 + i;
    const int col0 = ct * 128 + v * 64 + q;
    const half8* const ebi = eb + (size_t)ct * 8192;

    float cbsv[4];
#pragma unroll
    for (int nt = 0; nt < 4; ++nt) cbsv[nt] = cbs[col0 + nt * 16];

    f32x4 acc[4][4];
#pragma unroll
    for (int mt = 0; mt < 4; ++mt)
#pragma unroll
      for (int nt = 0; nt < 4; ++nt)
        acc[mt][nt] = (f32x4){0.f, 0.f, 0.f, 0.f};

#pragma unroll 2
    for (int kk = 0; kk < 8; ++kk) {
      half8 bh[4], bl[4], ah[4], al[4];
#pragma unroll
      for (int nt = 0; nt < 4; ++nt) {
        bh[nt] = ebi[nt * 1024 + kk * 128];
        bl[nt] = ebi[nt * 1024 + kk * 128 + 64];
      }
#pragma unroll
      for (int mt = 0; mt < 4; ++mt) {
        ah[mt] = Ab[mt * 1024 + kk * 128];
        al[mt] = Ab[mt * 1024 + kk * 128 + 64];
      }
#pragma unroll
      for (int mt = 0; mt < 4; ++mt)
#pragma unroll
        for (int nt = 0; nt < 4; ++nt) {
          acc[mt][nt] = __builtin_amdgcn_mfma_f32_16x16x32_f16(ah[mt], bh[nt], acc[mt][nt], 0, 0, 0);
          acc[mt][nt] = __builtin_amdgcn_mfma_f32_16x16x32_f16(ah[mt], bl[nt], acc[mt][nt], 0, 0, 0);
          acc[mt][nt] = __builtin_amdgcn_mfma_f32_16x16x32_f16(al[mt], bh[nt], acc[mt][nt], 0, 0, 0);
        }
    }

    // dist = 2^19*cb_sq - 2*acc; running (min,idx). Ascending nt / i =>
    // strict < keeps the lowest index on ties.
#pragma unroll
    for (int mt = 0; mt < 4; ++mt)
#pragma unroll
      for (int r = 0; r < 4; ++r) {
        float d = fmaf(-2.0f, acc[mt][0][r], cbsv[0]);
        unsigned cidx = (unsigned)col0;
#pragma unroll
        for (int nt = 1; nt < 4; ++nt) {
          float dn = fmaf(-2.0f, acc[mt][nt][r], cbsv[nt]);
          if (dn < d) { d = dn; cidx = (unsigned)(col0 + nt * 16); }
        }
        int ri = mt * 4 + r;
        if (d < rd[ri]) { rd[ri] = d; rc[ri] = cidx; }
      }
  }

  // Reduce: 16-lane groups hold 16 cols of the same rows; then combine the
  // 4 (v,p) candidates per row via LDS (overlaying dead A region).
  __syncthreads();                       // all waves done reading A
  float*    const redD = (float*)smem;   // [4][128]
  unsigned* const redC = (unsigned*)(smem + 2048);

#pragma unroll
  for (int ri = 0; ri < 16; ++ri) {
    float d = rd[ri]; unsigned cidx = rc[ri];
#pragma unroll
    for (int off = 1; off < 16; off <<= 1) {
      float od = __shfl_xor(d, off);
      unsigned oc = __shfl_xor(cidx, off);
      if (od < d || (od == d && oc < cidx)) { d = od; cidx = oc; }
    }
    if (q == 0) {
      int row = h * 64 + (ri >> 2) * 16 + quad * 4 + (ri & 3);
      redD[(w & 3) * 128 + row] = d;
      redC[(w & 3) * 128 + row] = cidx;
    }
  }
  __syncthreads();
  if (tid < 128) {
    float d0 = redD[tid]; unsigned c0 = redC[tid];
#pragma unroll
    for (int s = 1; s < 4; ++s) {
      float ds = redD[s * 128 + tid]; unsigned cs = redC[s * 128 + tid];
      if (ds < d0 || (ds == d0 && cs < c0)) { d0 = ds; c0 = cs; }
    }
    out[q0 + tid] = (int)c0;
  }
}

extern "C" void kernel_launch(void* const* d_in, const int* in_sizes, int n_in,
                              void* d_out, int out_size, void* d_ws, size_t ws_size,
                              hipStream_t stream) {
  const float* z  = (const float*)d_in[0];   // [32,32,32,256] fp32
  const float* cb = (const float*)d_in[1];   // [8192,256] fp32
  char* ws = (char*)d_ws;
  // ws layout: epk 8.4M (frag-major cb hi/lo) | cbs 32K @ +16M
  _Float16* epk = (_Float16*)(ws);
  float*    cbs = (float*)(ws + (size_t)16 * 1024 * 1024);

  hipLaunchKernelGGL(vq_prep_e, dim3(512), dim3(256), 0, stream, cb, epk, cbs);
  hipLaunchKernelGGL(vq_main,   dim3(256), dim3(512), 0, stream,
                     z, epk, cbs, (int*)d_out);
}